// Round 2
// baseline (235.137 us; speedup 1.0000x reference)
//
#include <hip/hip_runtime.h>
#include <cstdint>
#include <cstddef>

#define N_EMBD 1024
#define T_SEQ  2048
#define NBATCH 4
#define SPAN   256
#define C3     3072
// scale = sqrt(N_EMBD * SPAN) = 512

typedef float  floatx4 __attribute__((ext_vector_type(4)));
typedef __bf16 bf16x8  __attribute__((ext_vector_type(8)));

__device__ inline unsigned short f2bf(float f) {
    union { float f; unsigned u; } x; x.f = f;
    unsigned u = x.u;
    unsigned r = (u + 0x7fffu + ((u >> 16) & 1u)) >> 16;
    return (unsigned short)r;
}

typedef __attribute__((address_space(1))) const void GVOID;
typedef __attribute__((address_space(3))) void LVOID;
__device__ inline void gl2lds16(const void* g, void* l) {
    __builtin_amdgcn_global_load_lds((GVOID*)g, (LVOID*)l, 16, 0, 0);
}

// --- swizzled staging helpers -----------------------------------------------
// Rows of 64 bf16 (128 B = 8 chunks of 16 B). LDS chunk slot c of row r holds
// global chunk c ^ (r & 7); readers XOR the chunk index with (row & 7).
// gl2lds16 dest is wave-uniform base + lane*16 (HW rule), so one wave-load
// covers 8 rows; 8 waves x 64 lanes x 16B = 64 rows per round.

// 128 rows x 64 cols (2 rounds, 2 loads/thread)
__device__ inline void stage_half128(const unsigned short* g, size_t stride,
                                     unsigned short* lds, int lane, int wave) {
#pragma unroll
    for (int rnd = 0; rnd < 2; rnd++) {
        const int r = rnd * 64 + wave * 8 + (lane >> 3);
        const int chunk = (lane & 7) ^ (r & 7);
        gl2lds16(g + (size_t)r * stride + chunk * 8, &lds[(rnd * 64 + wave * 8) * 64]);
    }
}

// 64 rows x 64 cols (1 round, 1 load/thread)
__device__ inline void stage_half64(const unsigned short* g, size_t stride,
                                    unsigned short* lds, int lane, int wave) {
    const int r = wave * 8 + (lane >> 3);
    const int chunk = (lane & 7) ^ (r & 7);
    gl2lds16(g + (size_t)r * stride + chunk * 8, &lds[(wave * 8) * 64]);
}

// 64 rows x 64 cols, 256-thread WG (k_scores / k_sv)
__device__ inline void stage64x64(const unsigned short* g, size_t stride,
                                  unsigned short* lds, int lane, int wave) {
#pragma unroll
    for (int rnd = 0; rnd < 2; rnd++) {
        const int r = rnd * 32 + wave * 8 + (lane >> 3);
        const int chunk = (lane & 7) ^ (r & 7);
        gl2lds16(g + (size_t)r * stride + chunk * 8, &lds[(rnd * 32 + wave * 8) * 64]);
    }
}

// 128 rows x 64 cols, 256-thread WG (k_sv)
__device__ inline void stage128x64(const unsigned short* g, size_t stride,
                                   unsigned short* lds, int lane, int wave) {
#pragma unroll
    for (int rnd = 0; rnd < 4; rnd++) {
        const int r = rnd * 32 + wave * 8 + (lane >> 3);
        const int chunk = (lane & 7) ^ (r & 7);
        gl2lds16(g + (size_t)r * stride + chunk * 8, &lds[(rnd * 32 + wave * 8) * 64]);
    }
}

// Swizzled fragment read: 16B of row `row`, k-substep ks (0/1), q = lane>>4.
__device__ inline bf16x8 frag_ld(const unsigned short* buf, int row, int ks, int q) {
    return *(const bf16x8*)&buf[row * 64 + (((ks * 4 + q) ^ (row & 7)) * 8)];
}

// ---------------------------------------------------------------------------
// K0: fused conversions. blocks [0,8192): x fp32->bf16. blocks [8192,11264): W -> WbT.
__global__ __launch_bounds__(256) void k_prep(const float* __restrict__ x,
                                              unsigned short* __restrict__ Xb,
                                              const float* __restrict__ W,
                                              unsigned short* __restrict__ WbT) {
    __shared__ unsigned short t[32][33];
    if (blockIdx.x < 8192) {
        int i = (blockIdx.x * 256 + threadIdx.x) * 4;
        float4 v = *(const float4*)(x + i);
        ushort4 o;
        o.x = f2bf(v.x); o.y = f2bf(v.y); o.z = f2bf(v.z); o.w = f2bf(v.w);
        *(ushort4*)(Xb + i) = o;
    } else {
        int bid = blockIdx.x - 8192;
        int k0 = (bid & 31) * 32, n0 = (bid >> 5) * 32;
        int tx = threadIdx.x & 31, ty = threadIdx.x >> 5;
#pragma unroll
        for (int i = 0; i < 4; i++) {
            int k = k0 + ty + i * 8;
            t[ty + i * 8][tx] = f2bf(W[(size_t)k * C3 + n0 + tx]);
        }
        __syncthreads();
#pragma unroll
        for (int i = 0; i < 4; i++) {
            int n = n0 + ty + i * 8;
            WbT[(size_t)n * N_EMBD + k0 + tx] = t[tx][ty + i * 8];
        }
    }
}

// ---------------------------------------------------------------------------
// K1: unified QKV GEMM, 8-phase counted-vmcnt schedule (T2+T3+T4+T5).
// BM=256, BN=128, BK=64, 512 threads = 8 waves (2M x 4N), per-wave C 128x32.
// Grid: 512 QK-WGs (32 mt x 16 nt) + 256 V-WGs (4 ct x 64 tv) = 768 = 3 exact
// CU-rounds. LDS 96 KB double-buffer (buf0 = even K-tiles, buf1 = odd).
//
// Per 2 K-tiles (t0 even in buf0, t1 odd in buf1), 8 phases, each:
//   [ds_read subtile | stage 1 half-tile | s_barrier | MFMA x8 | s_barrier]
// Stage slot ledger (issue only after the region's last reader phase+barrier):
//   P1: A0(t1)->buf1   (buf1.A rows 0..127 last read prev P7)
//   P2: A1(t1)->buf1
//   P3: B0(t0+2)->buf0 (buf0.B last read P2)
//   P4: B1(t0+2)->buf0 ; vmcnt(2) -> guarantees buf1 = tile t1 fully landed
//   P5: A0(t0+2)->buf0 (buf0.A last read P3)
//   P6: A1(t0+2)->buf0
//   P7: B0(t1+2)->buf1 (buf1.B last read P6)
//   P8: B1(t1+2)->buf1 ; vmcnt(2) -> guarantees buf0 = tile t0+2 fully landed
// Loads/thread: A-half = 2, B-half = 1; 12 per iteration. vmcnt(2) allows the
// newest 2 loads (the 2 just-issued B halves) to stay in flight across the
// barrier — never drain to 0 except the last iteration's P4.
// NO __launch_bounds__ min-waves arg (r5 lesson: forced spills, 4.4x slower).
__global__ __launch_bounds__(512) void k_gemm(const unsigned short* __restrict__ Xb,
                                              const unsigned short* __restrict__ WbT,
                                              const float* __restrict__ bqkv,
                                              unsigned short* __restrict__ QK,
                                              unsigned short* __restrict__ Vt) {
    __shared__ unsigned short As[2][256 * 64];   // 64 KB
    __shared__ unsigned short Bs[2][128 * 64];   // 32 KB
    const int tid = threadIdx.x, lane = tid & 63, wave = tid >> 6;
    const int wm = wave >> 2, wn = wave & 3;
    const int n15 = lane & 15, q = lane >> 4;

    // bijective XCD swizzle (768 % 8 == 0)
    const int wg = (blockIdx.x & 7) * 96 + (blockIdx.x >> 3);
    const bool isV = (wg >= 512);

    const unsigned short* gA;
    const unsigned short* gB;
    int rowbase, colbase, nb;
    if (!isV) {
        const int mt = wg >> 4, nt = wg & 15;
        gA = Xb + (size_t)(mt * 256) * N_EMBD;     // 256 token rows
        gB = WbT + (size_t)(nt * 128) * N_EMBD;    // 128 channel rows
        rowbase = mt * 256; colbase = nt * 128; nb = nt * 128;
    } else {
        const int v = wg - 512;
        const int ct = v >> 6, tv = v & 63;
        const int t0 = tv * 128;
        gA = WbT + (size_t)(2048 + ct * 256) * N_EMBD; // 256 channel rows (acc rows)
        gB = Xb + (size_t)t0 * N_EMBD;                 // 128 token rows (acc cols)
        rowbase = (t0 >> 11) * 1024 + ct * 256;        // Vt row = b*1024 + c
        colbase = t0 & 2047;
        nb = 2048 + ct * 256;                          // bias indexed by acc ROW here
    }

    floatx4 acc[8][2] = {};

#define BAR __builtin_amdgcn_s_barrier()
#define MFMA8(MIBASE, NI)                                                          \
    __builtin_amdgcn_sched_barrier(0);                                             \
    __builtin_amdgcn_s_setprio(1);                                                 \
    _Pragma("unroll")                                                              \
    for (int ks = 0; ks < 2; ++ks)                                                 \
        _Pragma("unroll")                                                          \
        for (int mi = 0; mi < 4; ++mi)                                             \
            acc[(MIBASE) + mi][NI] = __builtin_amdgcn_mfma_f32_16x16x32_bf16(      \
                a[mi][ks], b[NI][ks], acc[(MIBASE) + mi][NI], 0, 0, 0);            \
    __builtin_amdgcn_s_setprio(0);                                                 \
    __builtin_amdgcn_sched_barrier(0);

    // ---- prologue: buf0 <- tile0 full, buf1 <- tile1 B halves
    stage_half128(gA,                    N_EMBD, As[0],            lane, wave);
    stage_half128(gA + 128 * N_EMBD,     N_EMBD, As[0] + 128 * 64, lane, wave);
    stage_half64 (gB,                    N_EMBD, Bs[0],            lane, wave);
    stage_half64 (gB + 64 * N_EMBD,      N_EMBD, Bs[0] + 64 * 64,  lane, wave);
    stage_half64 (gB + 64,               N_EMBD, Bs[1],            lane, wave);
    stage_half64 (gB + 64 + 64 * N_EMBD, N_EMBD, Bs[1] + 64 * 64,  lane, wave);
    asm volatile("s_waitcnt vmcnt(2)" ::: "memory"); // tile0 landed, tile1-B flying
    BAR;

#pragma unroll 1
    for (int it = 0; it < 8; ++it) {
        const int t0k = it * 128;      // k-offset (elements) of even tile
        const int t1k = t0k + 64;
        const bool last = (it == 7);
        bf16x8 a[4][2], b[2][2];

        // ================= even tile (buf0) =================
        // P1
#pragma unroll
        for (int mi = 0; mi < 4; ++mi)
#pragma unroll
            for (int ks = 0; ks < 2; ++ks)
                a[mi][ks] = frag_ld(As[0], wm * 128 + mi * 16 + n15, ks, q);
#pragma unroll
        for (int ks = 0; ks < 2; ++ks)
            b[0][ks] = frag_ld(Bs[0], wn * 32 + n15, ks, q);
        stage_half128(gA + t1k, N_EMBD, As[1], lane, wave);
        BAR;
        MFMA8(0, 0)
        BAR;
        // P2
#pragma unroll
        for (int ks = 0; ks < 2; ++ks)
            b[1][ks] = frag_ld(Bs[0], wn * 32 + 16 + n15, ks, q);
        stage_half128(gA + t1k + 128 * N_EMBD, N_EMBD, As[1] + 128 * 64, lane, wave);
        BAR;
        MFMA8(0, 1)
        BAR;
        // P3
#pragma unroll
        for (int mi = 0; mi < 4; ++mi)
#pragma unroll
            for (int ks = 0; ks < 2; ++ks)
                a[mi][ks] = frag_ld(As[0], wm * 128 + (mi + 4) * 16 + n15, ks, q);
        if (!last) stage_half64(gB + t0k + 128, N_EMBD, Bs[0], lane, wave);
        BAR;
        MFMA8(4, 1)
        BAR;
        // P4
        if (!last) stage_half64(gB + t0k + 128 + 64 * N_EMBD, N_EMBD, Bs[0] + 64 * 64, lane, wave);
        BAR;
        MFMA8(4, 0)
        if (last) { asm volatile("s_waitcnt vmcnt(0)" ::: "memory"); }
        else      { asm volatile("s_waitcnt vmcnt(2)" ::: "memory"); }
        BAR;

        // ================= odd tile (buf1) =================
        // P5
#pragma unroll
        for (int mi = 0; mi < 4; ++mi)
#pragma unroll
            for (int ks = 0; ks < 2; ++ks)
                a[mi][ks] = frag_ld(As[1], wm * 128 + mi * 16 + n15, ks, q);
#pragma unroll
        for (int ks = 0; ks < 2; ++ks)
            b[0][ks] = frag_ld(Bs[1], wn * 32 + n15, ks, q);
        if (!last) stage_half128(gA + t0k + 128, N_EMBD, As[0], lane, wave);
        BAR;
        MFMA8(0, 0)
        BAR;
        // P6
#pragma unroll
        for (int ks = 0; ks < 2; ++ks)
            b[1][ks] = frag_ld(Bs[1], wn * 32 + 16 + n15, ks, q);
        if (!last) stage_half128(gA + t0k + 128 + 128 * N_EMBD, N_EMBD, As[0] + 128 * 64, lane, wave);
        BAR;
        MFMA8(0, 1)
        BAR;
        // P7
#pragma unroll
        for (int mi = 0; mi < 4; ++mi)
#pragma unroll
            for (int ks = 0; ks < 2; ++ks)
                a[mi][ks] = frag_ld(As[1], wm * 128 + (mi + 4) * 16 + n15, ks, q);
        if (!last) stage_half64(gB + t1k + 128, N_EMBD, Bs[1], lane, wave);
        BAR;
        MFMA8(4, 1)
        BAR;
        // P8
        if (!last) stage_half64(gB + t1k + 128 + 64 * N_EMBD, N_EMBD, Bs[1] + 64 * 64, lane, wave);
        BAR;
        MFMA8(4, 0)
        if (!last) { asm volatile("s_waitcnt vmcnt(2)" ::: "memory"); }
        BAR;
    }
#undef MFMA8
#undef BAR

    // Unified epilogue. QK: bias by column. V: bias by (channel) row.
    unsigned short* base = isV ? Vt : QK;
#pragma unroll
    for (int mi = 0; mi < 8; ++mi) {
#pragma unroll
        for (int r = 0; r < 4; ++r) {
            const int arow = wm * 128 + mi * 16 + q * 4 + r;
            unsigned short* dst = base + (size_t)(rowbase + arow) * 2048 + colbase;
            const float rbias = bqkv[nb + arow];
#pragma unroll
            for (int ni = 0; ni < 2; ++ni) {
                const int acol = wn * 32 + ni * 16 + n15;
                const float bias = isV ? rbias : bqkv[nb + acol];
                dst[acol] = f2bf(acc[mi][ni][r] + bias);
            }
        }
    }
}

// ---------------------------------------------------------------------------
// K2: banded scores, 64x64 out tiles, BK=64. grid (jj=5, qb=32, b=4) = 640 WGs.
// S block layout: [(b*32+qb)*5+jj] -> 64x64 bf16 row-major.
__global__ __launch_bounds__(256) void k_scores(const unsigned short* __restrict__ QK,
                                                unsigned short* __restrict__ S) {
    const int jj = blockIdx.x, qb = blockIdx.y, b = blockIdx.z;
    const int jb = qb - 4 + jj;
    if (jb < 0) return;

    __shared__ unsigned short Qs[4096];
    __shared__ unsigned short Ks[4096];
    const int tid = threadIdx.x, lane = tid & 63, wave = tid >> 6;
    const int wr = wave >> 1, wc = wave & 1;
    const int n15 = lane & 15, q = lane >> 4;

    floatx4 acc[2][2] = {};

    const unsigned short* gQ = QK + ((size_t)(b * T_SEQ + qb * 64)) * 2048;
    const unsigned short* gK = QK + ((size_t)(b * T_SEQ + jb * 64)) * 2048 + 1024;

    for (int k0 = 0; k0 < N_EMBD; k0 += 64) {
        stage64x64(gQ + k0, 2048, Qs, lane, wave);
        stage64x64(gK + k0, 2048, Ks, lane, wave);
        __syncthreads();
#pragma unroll
        for (int s = 0; s < 2; s++) {
            bf16x8 a[2], bbf[2];
#pragma unroll
            for (int mi = 0; mi < 2; mi++) {
                const int row = wr * 32 + mi * 16 + n15;
                a[mi] = *(const bf16x8*)&Qs[row * 64 + (((s * 4 + q) ^ (row & 7)) * 8)];
            }
#pragma unroll
            for (int ni = 0; ni < 2; ni++) {
                const int row = wc * 32 + ni * 16 + n15;
                bbf[ni] = *(const bf16x8*)&Ks[row * 64 + (((s * 4 + q) ^ (row & 7)) * 8)];
            }
#pragma unroll
            for (int mi = 0; mi < 2; mi++)
#pragma unroll
                for (int ni = 0; ni < 2; ni++)
                    acc[mi][ni] = __builtin_amdgcn_mfma_f32_16x16x32_bf16(a[mi], bbf[ni], acc[mi][ni], 0, 0, 0);
        }
        __syncthreads();
    }

    unsigned short* Sb = S + (((size_t)(b * 32 + qb) * 5 + jj) << 12);
#pragma unroll
    for (int mi = 0; mi < 2; mi++)
#pragma unroll
        for (int ni = 0; ni < 2; ni++)
#pragma unroll
            for (int r = 0; r < 4; r++) {
                const int il = wr * 32 + mi * 16 + q * 4 + r;
                const int jl = wc * 32 + ni * 16 + n15;
                const int gi = qb * 64 + il, gj = jb * 64 + jl;
                const float v = ((gj <= gi) && (gj > gi - SPAN)) ? acc[mi][ni][r] * (1.0f / 512.0f) : 0.0f;
                Sb[il * 64 + jl] = f2bf(v);
            }
}

// ---------------------------------------------------------------------------
// K3: out[64 x 128] = sum_jj S(64x64) @ V(64x128). grid (cg=8, qb=32, b=4) = 1024 WGs.
__global__ __launch_bounds__(256) void k_sv(const unsigned short* __restrict__ S,
                                            const unsigned short* __restrict__ Vt,
                                            float* __restrict__ out) {
    const int cg = blockIdx.x, qb = blockIdx.y, b = blockIdx.z;
    const int c0 = cg * 128;

    __shared__ unsigned short Ss[4096];
    __shared__ unsigned short Vs[8192];
    const int tid = threadIdx.x, lane = tid & 63, wave = tid >> 6;
    const int wr = wave >> 1, wc = wave & 1;
    const int n15 = lane & 15, q = lane >> 4;

    floatx4 acc[2][4] = {};

    for (int jj = 0; jj < 5; jj++) {
        const int jb = qb - 4 + jj;
        if (jb < 0) continue;
        stage64x64(S + (((size_t)(b * 32 + qb) * 5 + jj) << 12), 64, Ss, lane, wave);
        stage128x64(Vt + ((size_t)(b * 1024 + c0)) * 2048 + jb * 64, 2048, Vs, lane, wave);
        __syncthreads();
#pragma unroll
        for (int s = 0; s < 2; s++) {
            bf16x8 a[2], bbf[4];
#pragma unroll
            for (int mi = 0; mi < 2; mi++) {
                const int row = wr * 32 + mi * 16 + n15;
                a[mi] = *(const bf16x8*)&Ss[row * 64 + (((s * 4 + q) ^ (row & 7)) * 8)];
            }
#pragma unroll
            for (int ni = 0; ni < 4; ni++) {
                const int row = wc * 64 + ni * 16 + n15;
                bbf[ni] = *(const bf16x8*)&Vs[row * 64 + (((s * 4 + q) ^ (row & 7)) * 8)];
            }
#pragma unroll
            for (int mi = 0; mi < 2; mi++)
#pragma unroll
                for (int ni = 0; ni < 4; ni++)
                    acc[mi][ni] = __builtin_amdgcn_mfma_f32_16x16x32_bf16(a[mi], bbf[ni], acc[mi][ni], 0, 0, 0);
        }
        __syncthreads();
    }

#pragma unroll
    for (int mi = 0; mi < 2; mi++)
#pragma unroll
        for (int ni = 0; ni < 4; ni++)
#pragma unroll
            for (int r = 0; r < 4; r++) {
                const int il = wr * 32 + mi * 16 + q * 4 + r;
                const int cl = wc * 64 + ni * 16 + n15;
                out[((size_t)(b * T_SEQ + qb * 64 + il)) * N_EMBD + c0 + cl] = acc[mi][ni][r];
            }
}

// ---------------------------------------------------------------------------
// K4: in-place LayerNorm over last dim (1024), one WG per row
__global__ __launch_bounds__(256) void k_ln(float* __restrict__ out,
                                            const float* __restrict__ w,
                                            const float* __restrict__ bias) {
    __shared__ float red[8];
    const int t = threadIdx.x;
    float* p = out + (size_t)blockIdx.x * N_EMBD;
    float4 v = ((const float4*)p)[t];
    float s  = v.x + v.y + v.z + v.w;
    float sq = v.x * v.x + v.y * v.y + v.z * v.z + v.w * v.w;
#pragma unroll
    for (int off = 32; off; off >>= 1) {
        s  += __shfl_down(s, off, 64);
        sq += __shfl_down(sq, off, 64);
    }
    const int wave = t >> 6, lane = t & 63;
    if (lane == 0) { red[wave] = s; red[4 + wave] = sq; }
    __syncthreads();
    const float ts = red[0] + red[1] + red[2] + red[3];
    const float tq = red[4] + red[5] + red[6] + red[7];
    const float mean = ts * (1.0f / N_EMBD);
    const float var  = tq * (1.0f / N_EMBD) - mean * mean;
    const float rs = rsqrtf(var + 1e-5f);
    float4 wv = ((const float4*)w)[t];
    float4 bv = ((const float4*)bias)[t];
    float4 o;
    o.x = (v.x - mean) * rs * wv.x + bv.x;
    o.y = (v.y - mean) * rs * wv.y + bv.y;
    o.z = (v.z - mean) * rs * wv.z + bv.z;
    o.w = (v.w - mean) * rs * wv.w + bv.w;
    ((float4*)p)[t] = o;
}

// ---------------------------------------------------------------------------
extern "C" void kernel_launch(void* const* d_in, const int* in_sizes, int n_in,
                              void* d_out, int out_size, void* d_ws, size_t ws_size,
                              hipStream_t stream) {
    const float* x  = (const float*)d_in[0];
    const float* W  = (const float*)d_in[1];
    const float* bq = (const float*)d_in[2];
    const float* lw = (const float*)d_in[3];
    const float* lb = (const float*)d_in[4];
    float* out = (float*)d_out;
    char* ws = (char*)d_ws;

    // workspace layout (bytes):
    //  Xb   @ 0          16,777,216  (8192x1024 bf16) — dead after GEMM
    //  Sbuf @ 0           5,242,880  (4*32*5 blocks of 64x64 bf16) — aliases Xb
    //  WbT  @ 16,777,216  6,291,456  (3072x1024 bf16)
    //  QK   @ 23,068,672 33,554,432  (8192x2048 bf16)
    //  Vt   @ 56,623,104 16,777,216  (4x1024x2048 bf16)
    //  total 73,400,320
    unsigned short* Xb   = (unsigned short*)(ws + 0);
    unsigned short* Sbuf = (unsigned short*)(ws + 0);
    unsigned short* WbT  = (unsigned short*)(ws + 16777216);
    unsigned short* QK   = (unsigned short*)(ws + 23068672);
    unsigned short* Vt   = (unsigned short*)(ws + 56623104);

    k_prep   <<<11264,           256, 0, stream>>>(x, Xb, W, WbT);
    k_gemm   <<<768,             512, 0, stream>>>(Xb, WbT, bq, QK, Vt);
    k_scores <<<dim3(5, 32, 4),  256, 0, stream>>>(QK, Sbuf);
    k_sv     <<<dim3(8, 32, 4),  256, 0, stream>>>(Sbuf, Vt, out);
    k_ln     <<<8192,            256, 0, stream>>>(out, lw, lb);
}

// Round 3
// 219.040 us; speedup vs baseline: 1.0735x; 1.0735x over previous
//
#include <hip/hip_runtime.h>
#include <cstdint>
#include <cstddef>

#define N_EMBD 1024
#define T_SEQ  2048
#define NBATCH 4
#define SPAN   256
#define C3     3072
// scale = sqrt(N_EMBD * SPAN) = 512

typedef float  floatx4 __attribute__((ext_vector_type(4)));
typedef __bf16 bf16x8  __attribute__((ext_vector_type(8)));

__device__ inline unsigned short f2bf(float f) {
    union { float f; unsigned u; } x; x.f = f;
    unsigned u = x.u;
    unsigned r = (u + 0x7fffu + ((u >> 16) & 1u)) >> 16;
    return (unsigned short)r;
}

typedef __attribute__((address_space(1))) const void GVOID;
typedef __attribute__((address_space(3))) void LVOID;
__device__ inline void gl2lds16(const void* g, void* l) {
    __builtin_amdgcn_global_load_lds((GVOID*)g, (LVOID*)l, 16, 0, 0);
}

// --- swizzled staging helpers -----------------------------------------------
// Rows of 64 bf16 (128 B = 8 chunks of 16 B). LDS chunk slot c of row r holds
// global chunk c ^ (r & 7); readers XOR the chunk index with (row & 7).
// gl2lds16 dest is wave-uniform base + lane*16 (HW rule), so one wave-load
// covers 8 rows; 8 waves x 64 lanes x 16B = 64 rows per round.

// 128 rows x 64 cols, 512-thread WG (2 rounds, 2 loads/thread)
__device__ inline void stage_half128(const unsigned short* g, size_t stride,
                                     unsigned short* lds, int lane, int wave) {
#pragma unroll
    for (int rnd = 0; rnd < 2; rnd++) {
        const int r = rnd * 64 + wave * 8 + (lane >> 3);
        const int chunk = (lane & 7) ^ (r & 7);
        gl2lds16(g + (size_t)r * stride + chunk * 8, &lds[(rnd * 64 + wave * 8) * 64]);
    }
}

// 64 rows x 64 cols, 256-thread WG (k_scores / k_sv)
__device__ inline void stage64x64(const unsigned short* g, size_t stride,
                                  unsigned short* lds, int lane, int wave) {
#pragma unroll
    for (int rnd = 0; rnd < 2; rnd++) {
        const int r = rnd * 32 + wave * 8 + (lane >> 3);
        const int chunk = (lane & 7) ^ (r & 7);
        gl2lds16(g + (size_t)r * stride + chunk * 8, &lds[(rnd * 32 + wave * 8) * 64]);
    }
}

// 128 rows x 64 cols, 256-thread WG (k_sv)
__device__ inline void stage128x64(const unsigned short* g, size_t stride,
                                   unsigned short* lds, int lane, int wave) {
#pragma unroll
    for (int rnd = 0; rnd < 4; rnd++) {
        const int r = rnd * 32 + wave * 8 + (lane >> 3);
        const int chunk = (lane & 7) ^ (r & 7);
        gl2lds16(g + (size_t)r * stride + chunk * 8, &lds[(rnd * 32 + wave * 8) * 64]);
    }
}

// Swizzled fragment read: 16B of row `row`, k-substep ks (0/1), q = lane>>4.
__device__ inline bf16x8 frag_ld(const unsigned short* buf, int row, int ks, int q) {
    return *(const bf16x8*)&buf[row * 64 + (((ks * 4 + q) ^ (row & 7)) * 8)];
}

// ---------------------------------------------------------------------------
// K0: fused conversions. blocks [0,8192): x fp32->bf16. blocks [8192,11264): W -> WbT.
__global__ __launch_bounds__(256) void k_prep(const float* __restrict__ x,
                                              unsigned short* __restrict__ Xb,
                                              const float* __restrict__ W,
                                              unsigned short* __restrict__ WbT) {
    __shared__ unsigned short t[32][33];
    if (blockIdx.x < 8192) {
        int i = (blockIdx.x * 256 + threadIdx.x) * 4;
        float4 v = *(const float4*)(x + i);
        ushort4 o;
        o.x = f2bf(v.x); o.y = f2bf(v.y); o.z = f2bf(v.z); o.w = f2bf(v.w);
        *(ushort4*)(Xb + i) = o;
    } else {
        int bid = blockIdx.x - 8192;
        int k0 = (bid & 31) * 32, n0 = (bid >> 5) * 32;
        int tx = threadIdx.x & 31, ty = threadIdx.x >> 5;
#pragma unroll
        for (int i = 0; i < 4; i++) {
            int k = k0 + ty + i * 8;
            t[ty + i * 8][tx] = f2bf(W[(size_t)k * C3 + n0 + tx]);
        }
        __syncthreads();
#pragma unroll
        for (int i = 0; i < 4; i++) {
            int n = n0 + ty + i * 8;
            WbT[(size_t)n * N_EMBD + k0 + tx] = t[tx][ty + i * 8];
        }
    }
}

// ---------------------------------------------------------------------------
// K1: unified QKV GEMM. BM=256, BN=128, BK=64, 512 threads = 8 waves (2M x 4N),
// per-wave C 128x32 (acc[8][2]). Grid 768 = 3 exact CU-rounds, XCD-swizzled.
// LDS 96 KB double-buffer.
//
// FAT-PHASE schedule (r2 post-mortem: 8 thin phases of 8 MFMA were
// barrier-bound at 21% MfmaUtil; m201 ratio = 8 MFMA/barrier). Per iteration
// (2 K-tiles t0->buf0, t1->buf1), 4 phases of 16 MFMA each:
//   P1: read a(A0,buf0)+b(B,buf0); stage buf1.A1<-t1       ; MFMA mi0-3
//   P2: read a(A1,buf0)          ; stage buf0.A0,B <- t0+2 ; MFMA mi4-7; vmcnt(4)
//   P3: read a(A0,buf1)+b(B,buf1); stage buf0.A1  <- t0+2  ; MFMA mi0-3
//   P4: read a(A1,buf1)          ; stage buf1.A0,B <- t1+2 ; MFMA mi4-7; vmcnt(4)
// b-frags persist P1->P2 (P2's stage overwrites Bs[0] AFTER b is in regs).
// WAR safety: phase P+1's stage is issued after phase P's closing barrier;
// phase P's ds_reads complete before its MFMA (compiler lgkmcnt) which is
// before the closing barrier. vmcnt(4) leaves only the current phase's 2
// stage units (4 loads/thread) in flight -> never drains to 0 mid-loop.
// NO sched_barrier(0) (m141: order-pinning regresses). setprio(1) on MFMA.
__global__ __launch_bounds__(512) void k_gemm(const unsigned short* __restrict__ Xb,
                                              const unsigned short* __restrict__ WbT,
                                              const float* __restrict__ bqkv,
                                              unsigned short* __restrict__ QK,
                                              unsigned short* __restrict__ Vt) {
    __shared__ unsigned short As[2][256 * 64];   // 64 KB
    __shared__ unsigned short Bs[2][128 * 64];   // 32 KB
    const int tid = threadIdx.x, lane = tid & 63, wave = tid >> 6;
    const int wm = wave >> 2, wn = wave & 3;
    const int n15 = lane & 15, q = lane >> 4;

    // bijective XCD swizzle (768 % 8 == 0)
    const int wg = (blockIdx.x & 7) * 96 + (blockIdx.x >> 3);
    const bool isV = (wg >= 512);

    const unsigned short* gA;
    const unsigned short* gB;
    int rowbase, colbase, nb;
    if (!isV) {
        const int mt = wg >> 4, nt = wg & 15;
        gA = Xb + (size_t)(mt * 256) * N_EMBD;     // 256 token rows
        gB = WbT + (size_t)(nt * 128) * N_EMBD;    // 128 channel rows
        rowbase = mt * 256; colbase = nt * 128; nb = nt * 128;
    } else {
        const int v = wg - 512;
        const int ct = v >> 6, tv = v & 63;
        const int t0 = tv * 128;
        gA = WbT + (size_t)(2048 + ct * 256) * N_EMBD; // 256 channel rows (acc rows)
        gB = Xb + (size_t)t0 * N_EMBD;                 // 128 token rows (acc cols)
        rowbase = (t0 >> 11) * 1024 + ct * 256;        // Vt row = b*1024 + c
        colbase = t0 & 2047;
        nb = 2048 + ct * 256;                          // bias indexed by acc ROW here
    }

    floatx4 acc[8][2] = {};

#define BAR __builtin_amdgcn_s_barrier()
#define MFMA16(MIBASE)                                                             \
    __builtin_amdgcn_s_setprio(1);                                                 \
    _Pragma("unroll")                                                              \
    for (int ks = 0; ks < 2; ++ks)                                                 \
        _Pragma("unroll")                                                          \
        for (int mi = 0; mi < 4; ++mi)                                             \
            _Pragma("unroll")                                                      \
            for (int ni = 0; ni < 2; ++ni)                                         \
                acc[(MIBASE) + mi][ni] = __builtin_amdgcn_mfma_f32_16x16x32_bf16(  \
                    a[mi][ks], b[ni][ks], acc[(MIBASE) + mi][ni], 0, 0, 0);        \
    __builtin_amdgcn_s_setprio(0);

    // ---- prologue: buf0 <- tile0 (A0,A1,B), buf1 <- tile1 (A0,B); A1(t1) in P1
    stage_half128(gA,                N_EMBD, As[0],            lane, wave);
    stage_half128(gA + 128 * N_EMBD, N_EMBD, As[0] + 128 * 64, lane, wave);
    stage_half128(gB,                N_EMBD, Bs[0],            lane, wave);
    stage_half128(gA + 64,           N_EMBD, As[1],            lane, wave);
    stage_half128(gB + 64,           N_EMBD, Bs[1],            lane, wave);
    asm volatile("s_waitcnt vmcnt(4)" ::: "memory"); // buf0 landed; buf1 (4) flying
    BAR;

#pragma unroll 1
    for (int it = 0; it < 8; ++it) {
        const int t0k = it * 128;      // k-offset of even tile (2it)
        const int t1k = t0k + 64;      // odd tile (2it+1)
        const bool last = (it == 7);
        bf16x8 a[4][2], b[2][2];

        // ---- P1: buf0 mi0-3 ----
#pragma unroll
        for (int mi = 0; mi < 4; ++mi)
#pragma unroll
            for (int ks = 0; ks < 2; ++ks)
                a[mi][ks] = frag_ld(As[0], wm * 128 + mi * 16 + n15, ks, q);
#pragma unroll
        for (int ni = 0; ni < 2; ++ni)
#pragma unroll
            for (int ks = 0; ks < 2; ++ks)
                b[ni][ks] = frag_ld(Bs[0], wn * 32 + ni * 16 + n15, ks, q);
        stage_half128(gA + t1k + 128 * N_EMBD, N_EMBD, As[1] + 128 * 64, lane, wave);
        BAR;
        MFMA16(0)
        BAR;

        // ---- P2: buf0 mi4-7 (b persists) ----
#pragma unroll
        for (int mi = 0; mi < 4; ++mi)
#pragma unroll
            for (int ks = 0; ks < 2; ++ks)
                a[mi][ks] = frag_ld(As[0], wm * 128 + (mi + 4) * 16 + n15, ks, q);
        if (!last) {
            stage_half128(gA + t0k + 128, N_EMBD, As[0], lane, wave);
            stage_half128(gB + t0k + 128, N_EMBD, Bs[0], lane, wave);
        }
        BAR;
        MFMA16(4)
        if (last) { asm volatile("s_waitcnt vmcnt(0)" ::: "memory"); }
        else      { asm volatile("s_waitcnt vmcnt(4)" ::: "memory"); }
        BAR;

        // ---- P3: buf1 mi0-3 ----
#pragma unroll
        for (int mi = 0; mi < 4; ++mi)
#pragma unroll
            for (int ks = 0; ks < 2; ++ks)
                a[mi][ks] = frag_ld(As[1], wm * 128 + mi * 16 + n15, ks, q);
#pragma unroll
        for (int ni = 0; ni < 2; ++ni)
#pragma unroll
            for (int ks = 0; ks < 2; ++ks)
                b[ni][ks] = frag_ld(Bs[1], wn * 32 + ni * 16 + n15, ks, q);
        if (!last) stage_half128(gA + t0k + 128 + 128 * N_EMBD, N_EMBD, As[0] + 128 * 64, lane, wave);
        BAR;
        MFMA16(0)
        BAR;

        // ---- P4: buf1 mi4-7 (b persists) ----
#pragma unroll
        for (int mi = 0; mi < 4; ++mi)
#pragma unroll
            for (int ks = 0; ks < 2; ++ks)
                a[mi][ks] = frag_ld(As[1], wm * 128 + (mi + 4) * 16 + n15, ks, q);
        if (!last) {
            stage_half128(gA + t1k + 128, N_EMBD, As[1], lane, wave);
            stage_half128(gB + t1k + 128, N_EMBD, Bs[1], lane, wave);
        }
        BAR;
        MFMA16(4)
        if (!last) { asm volatile("s_waitcnt vmcnt(4)" ::: "memory"); }
        BAR;
    }
#undef MFMA16
#undef BAR

    // Unified epilogue. QK: bias by column. V: bias by (channel) row.
    unsigned short* base = isV ? Vt : QK;
#pragma unroll
    for (int mi = 0; mi < 8; ++mi) {
#pragma unroll
        for (int r = 0; r < 4; ++r) {
            const int arow = wm * 128 + mi * 16 + q * 4 + r;
            unsigned short* dst = base + (size_t)(rowbase + arow) * 2048 + colbase;
            const float rbias = bqkv[nb + arow];
#pragma unroll
            for (int ni = 0; ni < 2; ++ni) {
                const int acol = wn * 32 + ni * 16 + n15;
                const float bias = isV ? rbias : bqkv[nb + acol];
                dst[acol] = f2bf(acc[mi][ni][r] + bias);
            }
        }
    }
}

// ---------------------------------------------------------------------------
// K2: banded scores, 64x64 out tiles, BK=64. grid (jj=5, qb=32, b=4) = 640 WGs.
// S block layout: [(b*32+qb)*5+jj] -> 64x64 bf16 row-major.
__global__ __launch_bounds__(256) void k_scores(const unsigned short* __restrict__ QK,
                                                unsigned short* __restrict__ S) {
    const int jj = blockIdx.x, qb = blockIdx.y, b = blockIdx.z;
    const int jb = qb - 4 + jj;
    if (jb < 0) return;

    __shared__ unsigned short Qs[4096];
    __shared__ unsigned short Ks[4096];
    const int tid = threadIdx.x, lane = tid & 63, wave = tid >> 6;
    const int wr = wave >> 1, wc = wave & 1;
    const int n15 = lane & 15, q = lane >> 4;

    floatx4 acc[2][2] = {};

    const unsigned short* gQ = QK + ((size_t)(b * T_SEQ + qb * 64)) * 2048;
    const unsigned short* gK = QK + ((size_t)(b * T_SEQ + jb * 64)) * 2048 + 1024;

    for (int k0 = 0; k0 < N_EMBD; k0 += 64) {
        stage64x64(gQ + k0, 2048, Qs, lane, wave);
        stage64x64(gK + k0, 2048, Ks, lane, wave);
        __syncthreads();
#pragma unroll
        for (int s = 0; s < 2; s++) {
            bf16x8 a[2], bbf[2];
#pragma unroll
            for (int mi = 0; mi < 2; mi++) {
                const int row = wr * 32 + mi * 16 + n15;
                a[mi] = *(const bf16x8*)&Qs[row * 64 + (((s * 4 + q) ^ (row & 7)) * 8)];
            }
#pragma unroll
            for (int ni = 0; ni < 2; ni++) {
                const int row = wc * 32 + ni * 16 + n15;
                bbf[ni] = *(const bf16x8*)&Ks[row * 64 + (((s * 4 + q) ^ (row & 7)) * 8)];
            }
#pragma unroll
            for (int mi = 0; mi < 2; mi++)
#pragma unroll
                for (int ni = 0; ni < 2; ni++)
                    acc[mi][ni] = __builtin_amdgcn_mfma_f32_16x16x32_bf16(a[mi], bbf[ni], acc[mi][ni], 0, 0, 0);
        }
        __syncthreads();
    }

    unsigned short* Sb = S + (((size_t)(b * 32 + qb) * 5 + jj) << 12);
#pragma unroll
    for (int mi = 0; mi < 2; mi++)
#pragma unroll
        for (int ni = 0; ni < 2; ni++)
#pragma unroll
            for (int r = 0; r < 4; r++) {
                const int il = wr * 32 + mi * 16 + q * 4 + r;
                const int jl = wc * 32 + ni * 16 + n15;
                const int gi = qb * 64 + il, gj = jb * 64 + jl;
                const float v = ((gj <= gi) && (gj > gi - SPAN)) ? acc[mi][ni][r] * (1.0f / 512.0f) : 0.0f;
                Sb[il * 64 + jl] = f2bf(v);
            }
}

// ---------------------------------------------------------------------------
// K3: out[64 x 128] = sum_jj S(64x64) @ V(64x128). grid (cg=8, qb=32, b=4) = 1024 WGs.
__global__ __launch_bounds__(256) void k_sv(const unsigned short* __restrict__ S,
                                            const unsigned short* __restrict__ Vt,
                                            float* __restrict__ out) {
    const int cg = blockIdx.x, qb = blockIdx.y, b = blockIdx.z;
    const int c0 = cg * 128;

    __shared__ unsigned short Ss[4096];
    __shared__ unsigned short Vs[8192];
    const int tid = threadIdx.x, lane = tid & 63, wave = tid >> 6;
    const int wr = wave >> 1, wc = wave & 1;
    const int n15 = lane & 15, q = lane >> 4;

    floatx4 acc[2][4] = {};

    for (int jj = 0; jj < 5; jj++) {
        const int jb = qb - 4 + jj;
        if (jb < 0) continue;
        stage64x64(S + (((size_t)(b * 32 + qb) * 5 + jj) << 12), 64, Ss, lane, wave);
        stage128x64(Vt + ((size_t)(b * 1024 + c0)) * 2048 + jb * 64, 2048, Vs, lane, wave);
        __syncthreads();
#pragma unroll
        for (int s = 0; s < 2; s++) {
            bf16x8 a[2], bbf[4];
#pragma unroll
            for (int mi = 0; mi < 2; mi++) {
                const int row = wr * 32 + mi * 16 + n15;
                a[mi] = *(const bf16x8*)&Ss[row * 64 + (((s * 4 + q) ^ (row & 7)) * 8)];
            }
#pragma unroll
            for (int ni = 0; ni < 4; ni++) {
                const int row = wc * 64 + ni * 16 + n15;
                bbf[ni] = *(const bf16x8*)&Vs[row * 64 + (((s * 4 + q) ^ (row & 7)) * 8)];
            }
#pragma unroll
            for (int mi = 0; mi < 2; mi++)
#pragma unroll
                for (int ni = 0; ni < 4; ni++)
                    acc[mi][ni] = __builtin_amdgcn_mfma_f32_16x16x32_bf16(a[mi], bbf[ni], acc[mi][ni], 0, 0, 0);
        }
        __syncthreads();
    }

#pragma unroll
    for (int mi = 0; mi < 2; mi++)
#pragma unroll
        for (int ni = 0; ni < 4; ni++)
#pragma unroll
            for (int r = 0; r < 4; r++) {
                const int il = wr * 32 + mi * 16 + q * 4 + r;
                const int cl = wc * 64 + ni * 16 + n15;
                out[((size_t)(b * T_SEQ + qb * 64 + il)) * N_EMBD + c0 + cl] = acc[mi][ni][r];
            }
}

// ---------------------------------------------------------------------------
// K4: in-place LayerNorm over last dim (1024), one WG per row
__global__ __launch_bounds__(256) void k_ln(float* __restrict__ out,
                                            const float* __restrict__ w,
                                            const float* __restrict__ bias) {
    __shared__ float red[8];
    const int t = threadIdx.x;
    float* p = out + (size_t)blockIdx.x * N_EMBD;
    float4 v = ((const float4*)p)[t];
    float s  = v.x + v.y + v.z + v.w;
    float sq = v.x * v.x + v.y * v.y + v.z * v.z + v.w * v.w;
#pragma unroll
    for (int off = 32; off; off >>= 1) {
        s  += __shfl_down(s, off, 64);
        sq += __shfl_down(sq, off, 64);
    }
    const int wave = t >> 6, lane = t & 63;
    if (lane == 0) { red[wave] = s; red[4 + wave] = sq; }
    __syncthreads();
    const float ts = red[0] + red[1] + red[2] + red[3];
    const float tq = red[4] + red[5] + red[6] + red[7];
    const float mean = ts * (1.0f / N_EMBD);
    const float var  = tq * (1.0f / N_EMBD) - mean * mean;
    const float rs = rsqrtf(var + 1e-5f);
    float4 wv = ((const float4*)w)[t];
    float4 bv = ((const float4*)bias)[t];
    float4 o;
    o.x = (v.x - mean) * rs * wv.x + bv.x;
    o.y = (v.y - mean) * rs * wv.y + bv.y;
    o.z = (v.z - mean) * rs * wv.z + bv.z;
    o.w = (v.w - mean) * rs * wv.w + bv.w;
    ((float4*)p)[t] = o;
}

// ---------------------------------------------------------------------------
extern "C" void kernel_launch(void* const* d_in, const int* in_sizes, int n_in,
                              void* d_out, int out_size, void* d_ws, size_t ws_size,
                              hipStream_t stream) {
    const float* x  = (const float*)d_in[0];
    const float* W  = (const float*)d_in[1];
    const float* bq = (const float*)d_in[2];
    const float* lw = (const float*)d_in[3];
    const float* lb = (const float*)d_in[4];
    float* out = (float*)d_out;
    char* ws = (char*)d_ws;

    // workspace layout (bytes):
    //  Xb   @ 0          16,777,216  (8192x1024 bf16) — dead after GEMM
    //  Sbuf @ 0           5,242,880  (4*32*5 blocks of 64x64 bf16) — aliases Xb
    //  WbT  @ 16,777,216  6,291,456  (3072x1024 bf16)
    //  QK   @ 23,068,672 33,554,432  (8192x2048 bf16)
    //  Vt   @ 56,623,104 16,777,216  (4x1024x2048 bf16)
    //  total 73,400,320
    unsigned short* Xb   = (unsigned short*)(ws + 0);
    unsigned short* Sbuf = (unsigned short*)(ws + 0);
    unsigned short* WbT  = (unsigned short*)(ws + 16777216);
    unsigned short* QK   = (unsigned short*)(ws + 23068672);
    unsigned short* Vt   = (unsigned short*)(ws + 56623104);

    k_prep   <<<11264,           256, 0, stream>>>(x, Xb, W, WbT);
    k_gemm   <<<768,             512, 0, stream>>>(Xb, WbT, bq, QK, Vt);
    k_scores <<<dim3(5, 32, 4),  256, 0, stream>>>(QK, Sbuf);
    k_sv     <<<dim3(8, 32, 4),  256, 0, stream>>>(Sbuf, Vt, out);
    k_ln     <<<8192,            256, 0, stream>>>(out, lw, lb);
}

// Round 4
// 195.797 us; speedup vs baseline: 1.2009x; 1.1187x over previous
//
#include <hip/hip_runtime.h>
#include <cstdint>
#include <cstddef>

#define N_EMBD 1024
#define T_SEQ  2048
#define NBATCH 4
#define SPAN   256
#define C3     3072
// scale = sqrt(N_EMBD * SPAN) = 512

typedef float  floatx4 __attribute__((ext_vector_type(4)));
typedef __bf16 bf16x8  __attribute__((ext_vector_type(8)));

__device__ inline unsigned short f2bf(float f) {
    union { float f; unsigned u; } x; x.f = f;
    unsigned u = x.u;
    unsigned r = (u + 0x7fffu + ((u >> 16) & 1u)) >> 16;
    return (unsigned short)r;
}

typedef __attribute__((address_space(1))) const void GVOID;
typedef __attribute__((address_space(3))) void LVOID;
__device__ inline void gl2lds16(const void* g, void* l) {
    __builtin_amdgcn_global_load_lds((GVOID*)g, (LVOID*)l, 16, 0, 0);
}

// --- swizzled staging helpers -----------------------------------------------
// 128 rows x 32 cols bf16. LDS chunk slot c of row r holds global chunk c^((r>>1)&3).
// Reader chunk offset: qk = ((lane>>4) ^ ((lane>>1)&3)) * 8.
__device__ inline void stage128x32(const unsigned short* g, size_t stride,
                                   unsigned short* lds, int lane, int wave) {
    const int r     = wave * 16 + (lane >> 2);
    const int chunk = (lane & 3) ^ ((r >> 1) & 3);
    const unsigned short* src = g + (size_t)r * stride + chunk * 8;
    gl2lds16(src,               &lds[(wave * 16) * 32]);
    gl2lds16(src + 64 * stride, &lds[(64 + wave * 16) * 32]);
}

// 64 rows x 64 cols bf16. Slot c of row r holds global chunk c^(r&7). 2 rounds.
__device__ inline void stage64x64(const unsigned short* g, size_t stride,
                                  unsigned short* lds, int lane, int wave) {
#pragma unroll
    for (int rnd = 0; rnd < 2; rnd++) {
        const int r = rnd * 32 + wave * 8 + (lane >> 3);
        const int chunk = (lane & 7) ^ (r & 7);
        gl2lds16(g + (size_t)r * stride + chunk * 8, &lds[(rnd * 32 + wave * 8) * 64]);
    }
}

// 128 rows x 64 cols bf16. 4 rounds.
__device__ inline void stage128x64(const unsigned short* g, size_t stride,
                                   unsigned short* lds, int lane, int wave) {
#pragma unroll
    for (int rnd = 0; rnd < 4; rnd++) {
        const int r = rnd * 32 + wave * 8 + (lane >> 3);
        const int chunk = (lane & 7) ^ (r & 7);
        gl2lds16(g + (size_t)r * stride + chunk * 8, &lds[(rnd * 32 + wave * 8) * 64]);
    }
}

// ---------------------------------------------------------------------------
// K0: fused conversions. blocks [0,8192): x fp32->bf16. blocks [8192,11264): W -> WbT.
__global__ __launch_bounds__(256) void k_prep(const float* __restrict__ x,
                                              unsigned short* __restrict__ Xb,
                                              const float* __restrict__ W,
                                              unsigned short* __restrict__ WbT) {
    __shared__ unsigned short t[32][33];
    if (blockIdx.x < 8192) {
        int i = (blockIdx.x * 256 + threadIdx.x) * 4;
        float4 v = *(const float4*)(x + i);
        ushort4 o;
        o.x = f2bf(v.x); o.y = f2bf(v.y); o.z = f2bf(v.z); o.w = f2bf(v.w);
        *(ushort4*)(Xb + i) = o;
    } else {
        int bid = blockIdx.x - 8192;
        int k0 = (bid & 31) * 32, n0 = (bid >> 5) * 32;
        int tx = threadIdx.x & 31, ty = threadIdx.x >> 5;
#pragma unroll
        for (int i = 0; i < 4; i++) {
            int k = k0 + ty + i * 8;
            t[ty + i * 8][tx] = f2bf(W[(size_t)k * C3 + n0 + tx]);
        }
        __syncthreads();
#pragma unroll
        for (int i = 0; i < 4; i++) {
            int n = n0 + ty + i * 8;
            WbT[(size_t)n * N_EMBD + k0 + tx] = t[tx][ty + i * 8];
        }
    }
}

// ---------------------------------------------------------------------------
// K1: unified QKV GEMM, 128x128 tile, BK=32, 16 KB LDS, grid 24x64.
// EXACT r0 version (71.4 us, MfmaUtil 29.5, ~2.3 WGs/CU cross-WG overlap).
// r2/r3 post-mortem: 8-phase/fat-phase 256x128 ports at 1 WG/CU were
// LDS-read-bound (0.63 ds_read_b128 per MFMA > pipe balance) and lost
// cross-WG TLP -> 87-97 us. Do NOT re-pipeline without per-wave 128x64 slabs.
//  bx < 16 : QK path. acc=[t][n], dst = QK, rowbase=m0, colbase=n0.
//  bx >= 16: V path, operands swapped at staging (mfma(b,a)=mfma(a,b)^T)
//            -> acc=[c][t], dst = Vt, rowbase=batch*1024+(n0-2048), colbase=m0&2047.
__global__ __launch_bounds__(256) void k_gemm(const unsigned short* __restrict__ Xb,
                                              const unsigned short* __restrict__ WbT,
                                              const float* __restrict__ bqkv,
                                              unsigned short* __restrict__ QK,
                                              unsigned short* __restrict__ Vt) {
    __shared__ unsigned short As[4096];
    __shared__ unsigned short Bs[4096];
    const int tid = threadIdx.x, lane = tid & 63, wave = tid >> 6;
    const int bx = blockIdx.x, m0 = blockIdx.y * 128;
    const bool isV = (bx >= 16);
    const int n0 = isV ? (2048 + (bx - 16) * 128) : (bx * 128);
    const int wr = wave >> 1, wc = wave & 1;

    floatx4 acc[4][4] = {};

    const unsigned short* gA = (isV ? WbT + (size_t)n0 * N_EMBD : Xb  + (size_t)m0 * N_EMBD);
    const unsigned short* gB = (isV ? Xb  + (size_t)m0 * N_EMBD : WbT + (size_t)n0 * N_EMBD);
    const int qk = ((lane >> 4) ^ ((lane >> 1) & 3)) * 8;
    const int ra = wr * 64 + (lane & 15);
    const int rb = wc * 64 + (lane & 15);

    for (int k0 = 0; k0 < N_EMBD; k0 += 32) {
        stage128x32(gA + k0, N_EMBD, As, lane, wave);
        stage128x32(gB + k0, N_EMBD, Bs, lane, wave);
        __syncthreads();
        bf16x8 a[4], b[4];
#pragma unroll
        for (int mi = 0; mi < 4; mi++) a[mi] = *(const bf16x8*)&As[(ra + mi * 16) * 32 + qk];
#pragma unroll
        for (int ni = 0; ni < 4; ni++) b[ni] = *(const bf16x8*)&Bs[(rb + ni * 16) * 32 + qk];
#pragma unroll
        for (int mi = 0; mi < 4; mi++)
#pragma unroll
            for (int ni = 0; ni < 4; ni++)
                acc[mi][ni] = __builtin_amdgcn_mfma_f32_16x16x32_bf16(a[mi], b[ni], acc[mi][ni], 0, 0, 0);
        __syncthreads();
    }

    // Unified epilogue.
    const int cn = lane & 15, q = lane >> 4;
    unsigned short* base = isV ? Vt : QK;
    const int rowbase = isV ? (((m0 >> 11) << 10) + (n0 - 2048)) : m0;
    const int colbase = isV ? (m0 & 2047) : n0;
#pragma unroll
    for (int mi = 0; mi < 4; mi++) {
#pragma unroll
        for (int r = 0; r < 4; r++) {
            const int arow = wr * 64 + mi * 16 + q * 4 + r;
            unsigned short* dst = base + (size_t)(rowbase + arow) * 2048 + colbase;
#pragma unroll
            for (int ni = 0; ni < 4; ni++) {
                const int acol = wc * 64 + ni * 16 + cn;
                const float bias = bqkv[n0 + (isV ? arow : acol)];
                dst[acol] = f2bf(acc[mi][ni][r] + bias);
            }
        }
    }
}

// ---------------------------------------------------------------------------
// K2: banded scores, 64x64 out tiles, BK=128 (2 k-steps per barrier-pair).
// 640 WGs 1D, XCD-chunked swizzle (chunk=80) so the 5 jj-WGs sharing a
// Q-block land on one XCD's L2. Accumulation order identical to BK=64 version.
// S block layout: [(b*32+qb)*5+jj] -> 64x64 bf16 row-major.
__global__ __launch_bounds__(256) void k_scores(const unsigned short* __restrict__ QK,
                                                unsigned short* __restrict__ S) {
    const int logical = (blockIdx.x & 7) * 80 + (blockIdx.x >> 3);
    const int jj = logical % 5;
    const int qb = (logical / 5) & 31;
    const int b  = logical / 160;
    const int jb = qb - 4 + jj;
    if (jb < 0) return;

    __shared__ unsigned short Qs[2][4096];
    __shared__ unsigned short Ks[2][4096];
    const int tid = threadIdx.x, lane = tid & 63, wave = tid >> 6;
    const int wr = wave >> 1, wc = wave & 1;
    const int n15 = lane & 15, q = lane >> 4;

    floatx4 acc[2][2] = {};

    const unsigned short* gQ = QK + ((size_t)(b * T_SEQ + qb * 64)) * 2048;
    const unsigned short* gK = QK + ((size_t)(b * T_SEQ + jb * 64)) * 2048 + 1024;

    for (int k0 = 0; k0 < N_EMBD; k0 += 128) {
        stage64x64(gQ + k0,      2048, Qs[0], lane, wave);
        stage64x64(gQ + k0 + 64, 2048, Qs[1], lane, wave);
        stage64x64(gK + k0,      2048, Ks[0], lane, wave);
        stage64x64(gK + k0 + 64, 2048, Ks[1], lane, wave);
        __syncthreads();
#pragma unroll
        for (int h = 0; h < 2; h++) {
#pragma unroll
            for (int s = 0; s < 2; s++) {
                bf16x8 a[2], bbf[2];
#pragma unroll
                for (int mi = 0; mi < 2; mi++) {
                    const int row = wr * 32 + mi * 16 + n15;
                    a[mi] = *(const bf16x8*)&Qs[h][row * 64 + (((s * 4 + q) ^ (row & 7)) * 8)];
                }
#pragma unroll
                for (int ni = 0; ni < 2; ni++) {
                    const int row = wc * 32 + ni * 16 + n15;
                    bbf[ni] = *(const bf16x8*)&Ks[h][row * 64 + (((s * 4 + q) ^ (row & 7)) * 8)];
                }
#pragma unroll
                for (int mi = 0; mi < 2; mi++)
#pragma unroll
                    for (int ni = 0; ni < 2; ni++)
                        acc[mi][ni] = __builtin_amdgcn_mfma_f32_16x16x32_bf16(a[mi], bbf[ni], acc[mi][ni], 0, 0, 0);
            }
        }
        __syncthreads();
    }

    unsigned short* Sb = S + (((size_t)(b * 32 + qb) * 5 + jj) << 12);
#pragma unroll
    for (int mi = 0; mi < 2; mi++)
#pragma unroll
        for (int ni = 0; ni < 2; ni++)
#pragma unroll
            for (int r = 0; r < 4; r++) {
                const int il = wr * 32 + mi * 16 + q * 4 + r;
                const int jl = wc * 32 + ni * 16 + n15;
                const int gi = qb * 64 + il, gj = jb * 64 + jl;
                const float v = ((gj <= gi) && (gj > gi - SPAN)) ? acc[mi][ni][r] * (1.0f / 512.0f) : 0.0f;
                Sb[il * 64 + jl] = f2bf(v);
            }
}

// ---------------------------------------------------------------------------
// K3: out[64 x 128] = sum_jj S(64x64) @ V(64x128). 1024 WGs 1D, XCD-chunked
// swizzle (chunk=128) so the 8 cg-WGs sharing an S-block land on one XCD.
// jj-tiles processed in pairs per barrier-pair (halves sync count).
__global__ __launch_bounds__(256) void k_sv(const unsigned short* __restrict__ S,
                                            const unsigned short* __restrict__ Vt,
                                            float* __restrict__ out) {
    const int logical = (blockIdx.x & 7) * 128 + (blockIdx.x >> 3);
    const int cg = logical & 7;
    const int qb = (logical >> 3) & 31;
    const int b  = logical >> 8;
    const int c0 = cg * 128;

    __shared__ unsigned short Ss[2][4096];
    __shared__ unsigned short Vs[2][8192];
    const int tid = threadIdx.x, lane = tid & 63, wave = tid >> 6;
    const int wr = wave >> 1, wc = wave & 1;
    const int n15 = lane & 15, q = lane >> 4;

    floatx4 acc[2][4] = {};

    const size_t vbase = ((size_t)(b * 1024 + c0)) * 2048;
    const size_t sbase = ((size_t)(b * 32 + qb) * 5) << 12;

    for (int j0 = 0; j0 < 5; j0 += 2) {
        const int nv = (j0 < 4) ? 2 : 1;
        bool val[2] = {false, false};
#pragma unroll
        for (int t = 0; t < 2; t++) {
            if (t < nv && (qb - 4 + j0 + t) >= 0) {
                val[t] = true;
                stage64x64 (S + sbase + ((size_t)(j0 + t) << 12), 64, Ss[t], lane, wave);
                stage128x64(Vt + vbase + (size_t)(qb - 4 + j0 + t) * 64, 2048, Vs[t], lane, wave);
            }
        }
        __syncthreads();
#pragma unroll
        for (int t = 0; t < 2; t++) {
            if (!val[t]) continue;
#pragma unroll
            for (int s = 0; s < 2; s++) {
                bf16x8 a[2], bbf[4];
#pragma unroll
                for (int mi = 0; mi < 2; mi++) {
                    const int row = wr * 32 + mi * 16 + n15;
                    a[mi] = *(const bf16x8*)&Ss[t][row * 64 + (((s * 4 + q) ^ (row & 7)) * 8)];
                }
#pragma unroll
                for (int ni = 0; ni < 4; ni++) {
                    const int row = wc * 64 + ni * 16 + n15;
                    bbf[ni] = *(const bf16x8*)&Vs[t][row * 64 + (((s * 4 + q) ^ (row & 7)) * 8)];
                }
#pragma unroll
                for (int mi = 0; mi < 2; mi++)
#pragma unroll
                    for (int ni = 0; ni < 4; ni++)
                        acc[mi][ni] = __builtin_amdgcn_mfma_f32_16x16x32_bf16(a[mi], bbf[ni], acc[mi][ni], 0, 0, 0);
            }
        }
        __syncthreads();
    }

#pragma unroll
    for (int mi = 0; mi < 2; mi++)
#pragma unroll
        for (int ni = 0; ni < 4; ni++)
#pragma unroll
            for (int r = 0; r < 4; r++) {
                const int il = wr * 32 + mi * 16 + q * 4 + r;
                const int cl = wc * 64 + ni * 16 + n15;
                out[((size_t)(b * T_SEQ + qb * 64 + il)) * N_EMBD + c0 + cl] = acc[mi][ni][r];
            }
}

// ---------------------------------------------------------------------------
// K4: in-place LayerNorm over last dim (1024), one WG per row
__global__ __launch_bounds__(256) void k_ln(float* __restrict__ out,
                                            const float* __restrict__ w,
                                            const float* __restrict__ bias) {
    __shared__ float red[8];
    const int t = threadIdx.x;
    float* p = out + (size_t)blockIdx.x * N_EMBD;
    float4 v = ((const float4*)p)[t];
    float s  = v.x + v.y + v.z + v.w;
    float sq = v.x * v.x + v.y * v.y + v.z * v.z + v.w * v.w;
#pragma unroll
    for (int off = 32; off; off >>= 1) {
        s  += __shfl_down(s, off, 64);
        sq += __shfl_down(sq, off, 64);
    }
    const int wave = t >> 6, lane = t & 63;
    if (lane == 0) { red[wave] = s; red[4 + wave] = sq; }
    __syncthreads();
    const float ts = red[0] + red[1] + red[2] + red[3];
    const float tq = red[4] + red[5] + red[6] + red[7];
    const float mean = ts * (1.0f / N_EMBD);
    const float var  = tq * (1.0f / N_EMBD) - mean * mean;
    const float rs = rsqrtf(var + 1e-5f);
    float4 wv = ((const float4*)w)[t];
    float4 bv = ((const float4*)bias)[t];
    float4 o;
    o.x = (v.x - mean) * rs * wv.x + bv.x;
    o.y = (v.y - mean) * rs * wv.y + bv.y;
    o.z = (v.z - mean) * rs * wv.z + bv.z;
    o.w = (v.w - mean) * rs * wv.w + bv.w;
    ((float4*)p)[t] = o;
}

// ---------------------------------------------------------------------------
extern "C" void kernel_launch(void* const* d_in, const int* in_sizes, int n_in,
                              void* d_out, int out_size, void* d_ws, size_t ws_size,
                              hipStream_t stream) {
    const float* x  = (const float*)d_in[0];
    const float* W  = (const float*)d_in[1];
    const float* bq = (const float*)d_in[2];
    const float* lw = (const float*)d_in[3];
    const float* lb = (const float*)d_in[4];
    float* out = (float*)d_out;
    char* ws = (char*)d_ws;

    // workspace layout (bytes):
    //  Xb   @ 0          16,777,216  (8192x1024 bf16) — dead after GEMM
    //  Sbuf @ 0           5,242,880  (4*32*5 blocks of 64x64 bf16) — aliases Xb
    //  WbT  @ 16,777,216  6,291,456  (3072x1024 bf16)
    //  QK   @ 23,068,672 33,554,432  (8192x2048 bf16)
    //  Vt   @ 56,623,104 16,777,216  (4x1024x2048 bf16)
    //  total 73,400,320
    unsigned short* Xb   = (unsigned short*)(ws + 0);
    unsigned short* Sbuf = (unsigned short*)(ws + 0);
    unsigned short* WbT  = (unsigned short*)(ws + 16777216);
    unsigned short* QK   = (unsigned short*)(ws + 23068672);
    unsigned short* Vt   = (unsigned short*)(ws + 56623104);

    k_prep   <<<11264,           256, 0, stream>>>(x, Xb, W, WbT);
    k_gemm   <<<dim3(24, 64),    256, 0, stream>>>(Xb, WbT, bq, QK, Vt);
    k_scores <<<640,             256, 0, stream>>>(QK, Sbuf);
    k_sv     <<<1024,            256, 0, stream>>>(Sbuf, Vt, out);
    k_ln     <<<8192,            256, 0, stream>>>(out, lw, lb);
}